// Round 1
// baseline (181.787 us; speedup 1.0000x reference)
//
#include <hip/hip_runtime.h>
#include <math.h>

#define BATCH 4
#define S0 (540 * 960)

__device__ __forceinline__ int reflect_idx(int i, int n) {
    if (i < 0) i = -i;
    if (i >= n) i = 2 * n - 2 - i;
    return i;
}

// --------------------------------------------------------------------------
// DWT: each thread computes one output pixel of all 4 bands from a 4x4 patch.
// Bands stored row-major H2 x W2 inside a per-batch slot of S0 elements.
// --------------------------------------------------------------------------
__global__ void dwt_kernel(const float* __restrict__ src, long srcBatchStride,
                           int H, int W,
                           float* __restrict__ outA, float* __restrict__ outH,
                           float* __restrict__ outV, float* __restrict__ outD,
                           int H2, int W2)
{
    const float LO0 =  0.48296291314469f,  LO1 =  0.836516303737469f,
                LO2 =  0.224143868041857f, LO3 = -0.129409522550921f;
    const float HI0 = -0.129409522550921f, HI1 = -0.224143868041857f,
                HI2 =  0.836516303737469f, HI3 = -0.48296291314469f;

    int x = blockIdx.x * blockDim.x + threadIdx.x;
    int y = blockIdx.y * blockDim.y + threadIdx.y;
    int b = blockIdx.z;
    if (x >= W2 || y >= H2) return;

    const float* s = src + (long)b * srcBatchStride;

    int r0 = reflect_idx(2 * y - 1, H);
    int r1 = reflect_idx(2 * y + 0, H);
    int r2 = reflect_idx(2 * y + 1, H);
    int r3 = reflect_idx(2 * y + 2, H);
    int c[4];
    #pragma unroll
    for (int l = 0; l < 4; ++l) c[l] = reflect_idx(2 * x + l - 1, W);

    float vlo[4], vhi[4];
    #pragma unroll
    for (int l = 0; l < 4; ++l) {
        float p0 = s[(long)r0 * W + c[l]];
        float p1 = s[(long)r1 * W + c[l]];
        float p2 = s[(long)r2 * W + c[l]];
        float p3 = s[(long)r3 * W + c[l]];
        vlo[l] = LO0 * p0 + LO1 * p1 + LO2 * p2 + LO3 * p3;
        vhi[l] = HI0 * p0 + HI1 * p1 + HI2 * p2 + HI3 * p3;
    }
    float a_  = LO0 * vlo[0] + LO1 * vlo[1] + LO2 * vlo[2] + LO3 * vlo[3];
    float h_  = LO0 * vhi[0] + LO1 * vhi[1] + LO2 * vhi[2] + LO3 * vhi[3];
    float v_  = HI0 * vlo[0] + HI1 * vlo[1] + HI2 * vlo[2] + HI3 * vlo[3];
    float d_  = HI0 * vhi[0] + HI1 * vhi[1] + HI2 * vhi[2] + HI3 * vhi[3];

    long o = (long)b * S0 + (long)y * W2 + x;
    outA[o] = a_;
    outH[o] = h_;
    outV[o] = v_;
    outD[o] = d_;
}

// --------------------------------------------------------------------------
// Decouple (pointwise, recomputed on demand)
// --------------------------------------------------------------------------
__device__ __forceinline__ void decouple6(float oh, float ov, float od,
                                          float th, float tv, float td,
                                          float& Rh, float& Rv, float& Rd,
                                          float& Ah, float& Av, float& Ad)
{
    const float EPS = 1e-30f;
    const float COS1SQ = 0.9996954135095479f;

    float kh = th / (oh + EPS); kh = fminf(fmaxf(kh, 0.f), 1.f);
    float kv = tv / (ov + EPS); kv = fminf(fmaxf(kv, 0.f), 1.f);
    float kd = td / (od + EPS); kd = fminf(fmaxf(kd, 0.f), 1.f);
    float rh = kh * oh, rv = kv * ov, rd = kd * od;

    float ot = oh * th + ov * tv;
    bool flag = (ot >= 0.f) &&
                (ot * ot >= COS1SQ * (oh * oh + ov * ov) * (th * th + tv * tv));
    if (flag) {
        if (rh > 0.f) rh = fminf(rh * 100.f, th);
        if (rh < 0.f) rh = fmaxf(rh * 100.f, th);
        if (rv > 0.f) rv = fminf(rv * 100.f, tv);
        if (rv < 0.f) rv = fmaxf(rv * 100.f, tv);
        if (rd > 0.f) rd = fminf(rd * 100.f, td);
        if (rd < 0.f) rd = fmaxf(rd * 100.f, td);
    }
    Rh = rh; Rv = rv; Rd = rd;
    Ah = th - rh; Av = tv - rv; Ad = td - rd;
}

// --------------------------------------------------------------------------
// Fused decouple + CSF-den + CM-num reduction for one scale.
// acc layout: [BATCH][4 scales][6] = {den_h,den_v,den_d,num_h,num_v,num_d}
// --------------------------------------------------------------------------
__global__ void reduce_kernel(const float* __restrict__ POh, const float* __restrict__ POv,
                              const float* __restrict__ POd, const float* __restrict__ PTh,
                              const float* __restrict__ PTv, const float* __restrict__ PTd,
                              int H2, int W2, int left, int top, int right, int bottom,
                              float rfh, float rfv, float rfd,
                              float* __restrict__ acc, int scale)
{
    int x = blockIdx.x * blockDim.x + threadIdx.x;
    int y = blockIdx.y * blockDim.y + threadIdx.y;
    int b = blockIdx.z;

    float denh = 0.f, denv = 0.f, dend = 0.f;
    float numh = 0.f, numv = 0.f, numd = 0.f;

    if (x < W2 && y < H2) {
        bool interior = (x >= left) && (x < right) && (y >= top) && (y < bottom);
        if (interior) {
            long base = (long)b * S0;
            long o = base + (long)y * W2 + x;
            float oh = POh[o], ov = POv[o], od = POd[o];
            float th = PTh[o], tv = PTv[o], td = PTd[o];

            float t;
            t = fabsf(rfh * oh); denh = t * t * t;
            t = fabsf(rfv * ov); denv = t * t * t;
            t = fabsf(rfd * od); dend = t * t * t;

            float thrh = 0.f, thrv = 0.f, thrd = 0.f;
            float Rh = 0.f, Rv = 0.f, Rd = 0.f;
            #pragma unroll
            for (int dy = -1; dy <= 1; ++dy) {
                int yy = reflect_idx(y + dy, H2);
                #pragma unroll
                for (int dx = -1; dx <= 1; ++dx) {
                    int xx = reflect_idx(x + dx, W2);
                    long q = base + (long)yy * W2 + xx;
                    float rh, rv, rd, ah, av, ad;
                    decouple6(POh[q], POv[q], POd[q], PTh[q], PTv[q], PTd[q],
                              rh, rv, rd, ah, av, ad);
                    float w = (dx == 0 && dy == 0) ? (1.f / 15.f) : (1.f / 30.f);
                    thrh += w * fabsf(rfh * ah);
                    thrv += w * fabsf(rfv * av);
                    thrd += w * fabsf(rfd * ad);
                    if (dx == 0 && dy == 0) { Rh = rh; Rv = rv; Rd = rd; }
                }
            }
            t = fmaxf(fabsf(rfh * Rh) - thrh, 0.f); numh = t * t * t;
            t = fmaxf(fabsf(rfv * Rv) - thrv, 0.f); numv = t * t * t;
            t = fmaxf(fabsf(rfd * Rd) - thrd, 0.f); numd = t * t * t;
        }
    }

    // block reduction: block is (64,4) -> 4 waves, wave = threadIdx.y
    float vals[6] = {denh, denv, dend, numh, numv, numd};
    #pragma unroll
    for (int i = 0; i < 6; ++i) {
        float v = vals[i];
        #pragma unroll
        for (int off = 32; off > 0; off >>= 1) v += __shfl_down(v, off, 64);
        vals[i] = v;
    }
    __shared__ float smem[4][6];
    if (threadIdx.x == 0) {
        #pragma unroll
        for (int i = 0; i < 6; ++i) smem[threadIdx.y][i] = vals[i];
    }
    __syncthreads();
    int tid = threadIdx.y * 64 + threadIdx.x;
    if (tid < 6) {
        float s = smem[0][tid] + smem[1][tid] + smem[2][tid] + smem[3][tid];
        atomicAdd(&acc[((long)b * 4 + scale) * 6 + tid], s);
    }
}

__global__ void zero_kernel(float* __restrict__ acc)
{
    int i = threadIdx.x;
    if (i < BATCH * 4 * 6) acc[i] = 0.f;
}

__global__ void final_kernel(const float* __restrict__ acc, float* __restrict__ out,
                             float c0, float c1, float c2, float c3)
{
    int b = threadIdx.x;
    if (b >= BATCH) return;
    float cs[4] = {c0, c1, c2, c3};
    float num = 0.f, den = 0.f;
    for (int s = 0; s < 4; ++s) {
        const float* a = acc + ((long)b * 4 + s) * 6;
        den += cbrtf(a[0]) + cbrtf(a[1]) + cbrtf(a[2]) + cs[s];
        num += cbrtf(a[3]) + cbrtf(a[4]) + cbrtf(a[5]) + cs[s];
    }
    const float lim = 1e-10f;  // 1e-10 * (W*H)/(1920*1080) with W=1920,H=1080
    if (num < lim) num = 0.f;
    if (den < lim) den = 0.f;
    out[b] = (den == 0.f) ? 1.f : num / den;
}

// --------------------------------------------------------------------------
extern "C" void kernel_launch(void* const* d_in, const int* in_sizes, int n_in,
                              void* d_out, int out_size, void* d_ws, size_t ws_size,
                              hipStream_t stream)
{
    const float* Xref = (const float*)d_in[0];
    const float* Xdst = (const float*)d_in[1];
    float* out = (float*)d_out;
    float* ws  = (float*)d_ws;

    // workspace layout (floats): 10 buffers of BATCH*S0 + accumulators
    float* aRefA = ws + (long)0 * BATCH * S0;
    float* aRefB = ws + (long)1 * BATCH * S0;
    float* aDstA = ws + (long)2 * BATCH * S0;
    float* aDstB = ws + (long)3 * BATCH * S0;
    float* Oh    = ws + (long)4 * BATCH * S0;
    float* Ov    = ws + (long)5 * BATCH * S0;
    float* Od    = ws + (long)6 * BATCH * S0;
    float* Th    = ws + (long)7 * BATCH * S0;
    float* Tv    = ws + (long)8 * BATCH * S0;
    float* Td    = ws + (long)9 * BATCH * S0;
    float* acc   = ws + (long)10 * BATCH * S0;

    zero_kernel<<<dim3(1), dim3(128), 0, stream>>>(acc);

    static const float RF[4][3] = {
        {0.017382f, 0.017382f, 0.005891f},
        {0.031985f, 0.031985f, 0.014299f},
        {0.043373f, 0.043373f, 0.024397f},
        {0.045673f, 0.045673f, 0.031313f}};

    int H = 1080, W = 1920;
    long srcStride = (long)H * W;
    const float* sR = Xref;
    const float* sD = Xdst;
    float* pingR[2] = {aRefA, aRefB};
    float* pingD[2] = {aDstA, aDstB};
    float cs[4];

    for (int s = 0; s < 4; ++s) {
        int H2 = (H + 1) / 2, W2 = (W + 1) / 2;
        float* oR = pingR[s & 1];
        float* oD = pingD[s & 1];

        dim3 blk(64, 4), grd((W2 + 63) / 64, (H2 + 3) / 4, BATCH);
        dwt_kernel<<<grd, blk, 0, stream>>>(sR, srcStride, H, W, oR, Oh, Ov, Od, H2, W2);
        dwt_kernel<<<grd, blk, 0, stream>>>(sD, srcStride, H, W, oD, Th, Tv, Td, H2, W2);

        int left   = (int)floor((double)W2 * 0.1 - 0.5);
        int top    = (int)floor((double)H2 * 0.1 - 0.5);
        int right  = W2 - left;
        int bottom = H2 - top;

        reduce_kernel<<<grd, blk, 0, stream>>>(Oh, Ov, Od, Th, Tv, Td,
                                               H2, W2, left, top, right, bottom,
                                               RF[s][0], RF[s][1], RF[s][2], acc, s);

        cs[s] = 3.0f * cbrtf((float)((long)(bottom - top) * (right - left)) / 32.0f);

        sR = oR; sD = oD; srcStride = S0;
        H = H2; W = W2;
    }

    final_kernel<<<dim3(1), dim3(64), 0, stream>>>(acc, out, cs[0], cs[1], cs[2], cs[3]);
}

// Round 2
// 147.484 us; speedup vs baseline: 1.2326x; 1.2326x over previous
//
#include <hip/hip_runtime.h>
#include <math.h>

#define BATCH 4
#define S0 (540 * 960)

__device__ __forceinline__ int reflect_idx(int i, int n) {
    if (i < 0) i = -i;
    if (i >= n) i = 2 * n - 2 - i;
    return i;
}

// --------------------------------------------------------------------------
// DWT: each thread computes one output pixel of all 4 bands from a 4x4 patch.
// Bands stored row-major H2 x W2 inside a per-batch slot of S0 elements.
// --------------------------------------------------------------------------
__global__ void dwt_kernel(const float* __restrict__ src, long srcBatchStride,
                           int H, int W,
                           float* __restrict__ outA, float* __restrict__ outH,
                           float* __restrict__ outV, float* __restrict__ outD,
                           int H2, int W2)
{
    const float LO0 =  0.48296291314469f,  LO1 =  0.836516303737469f,
                LO2 =  0.224143868041857f, LO3 = -0.129409522550921f;
    const float HI0 = -0.129409522550921f, HI1 = -0.224143868041857f,
                HI2 =  0.836516303737469f, HI3 = -0.48296291314469f;

    int x = blockIdx.x * blockDim.x + threadIdx.x;
    int y = blockIdx.y * blockDim.y + threadIdx.y;
    int b = blockIdx.z;
    if (x >= W2 || y >= H2) return;

    const float* s = src + (long)b * srcBatchStride;

    int r0 = reflect_idx(2 * y - 1, H);
    int r1 = reflect_idx(2 * y + 0, H);
    int r2 = reflect_idx(2 * y + 1, H);
    int r3 = reflect_idx(2 * y + 2, H);
    int c[4];
    #pragma unroll
    for (int l = 0; l < 4; ++l) c[l] = reflect_idx(2 * x + l - 1, W);

    float vlo[4], vhi[4];
    #pragma unroll
    for (int l = 0; l < 4; ++l) {
        float p0 = s[(long)r0 * W + c[l]];
        float p1 = s[(long)r1 * W + c[l]];
        float p2 = s[(long)r2 * W + c[l]];
        float p3 = s[(long)r3 * W + c[l]];
        vlo[l] = LO0 * p0 + LO1 * p1 + LO2 * p2 + LO3 * p3;
        vhi[l] = HI0 * p0 + HI1 * p1 + HI2 * p2 + HI3 * p3;
    }
    float a_  = LO0 * vlo[0] + LO1 * vlo[1] + LO2 * vlo[2] + LO3 * vlo[3];
    float h_  = LO0 * vhi[0] + LO1 * vhi[1] + LO2 * vhi[2] + LO3 * vhi[3];
    float v_  = HI0 * vlo[0] + HI1 * vlo[1] + HI2 * vlo[2] + HI3 * vlo[3];
    float d_  = HI0 * vhi[0] + HI1 * vhi[1] + HI2 * vhi[2] + HI3 * vhi[3];

    long o = (long)b * S0 + (long)y * W2 + x;
    outA[o] = a_;
    outH[o] = h_;
    outV[o] = v_;
    outD[o] = d_;
}

// --------------------------------------------------------------------------
// Decouple (pointwise)
// --------------------------------------------------------------------------
__device__ __forceinline__ void decouple6(float oh, float ov, float od,
                                          float th, float tv, float td,
                                          float& Rh, float& Rv, float& Rd,
                                          float& Ah, float& Av, float& Ad)
{
    const float EPS = 1e-30f;
    const float COS1SQ = 0.9996954135095479f;

    float kh = th / (oh + EPS); kh = fminf(fmaxf(kh, 0.f), 1.f);
    float kv = tv / (ov + EPS); kv = fminf(fmaxf(kv, 0.f), 1.f);
    float kd = td / (od + EPS); kd = fminf(fmaxf(kd, 0.f), 1.f);
    float rh = kh * oh, rv = kv * ov, rd = kd * od;

    float ot = oh * th + ov * tv;
    bool flag = (ot >= 0.f) &&
                (ot * ot >= COS1SQ * (oh * oh + ov * ov) * (th * th + tv * tv));
    if (flag) {
        if (rh > 0.f) rh = fminf(rh * 100.f, th);
        if (rh < 0.f) rh = fmaxf(rh * 100.f, th);
        if (rv > 0.f) rv = fminf(rv * 100.f, tv);
        if (rv < 0.f) rv = fmaxf(rv * 100.f, tv);
        if (rd > 0.f) rd = fminf(rd * 100.f, td);
        if (rd < 0.f) rd = fmaxf(rd * 100.f, td);
    }
    Rh = rh; Rv = rv; Rd = rd;
    Ah = th - rh; Av = tv - rv; Ad = td - rd;
}

// --------------------------------------------------------------------------
// Fused decouple + CSF-den + CM-num reduction for one scale.
// LDS-staged: decouple computed ONCE per pixel (halo tile), 3x3 conv from LDS.
// Grid covers the interior rectangle only.
// acc layout: [BATCH][4 scales][6] = {den_h,den_v,den_d,num_h,num_v,num_d}
// --------------------------------------------------------------------------
#define RBX 32
#define RBY 8
#define HTW (RBX + 2)   // 34
#define HTH (RBY + 2)   // 10
#define HTP 36          // padded row stride

__global__ __launch_bounds__(RBX* RBY) void
reduce_kernel(const float* __restrict__ POh, const float* __restrict__ POv,
              const float* __restrict__ POd, const float* __restrict__ PTh,
              const float* __restrict__ PTv, const float* __restrict__ PTd,
              int H2, int W2, int left, int top, int right, int bottom,
              float rfh, float rfv, float rfd,
              float* __restrict__ acc, int scale)
{
    __shared__ float sh[HTH][HTP], sv[HTH][HTP], sd[HTH][HTP];
    __shared__ float srh[HTH][HTP], srv[HTH][HTP], srd[HTH][HTP];

    int b = blockIdx.z;
    long base = (long)b * S0;
    int x0 = left + blockIdx.x * RBX;
    int y0 = top + blockIdx.y * RBY;

    int tid = threadIdx.y * RBX + threadIdx.x;

    // stage halo tile: one decouple per pixel
    for (int i = tid; i < HTW * HTH; i += RBX * RBY) {
        int lx = i % HTW, ly = i / HTW;
        int xx = min(max(x0 - 1 + lx, 0), W2 - 1);
        int yy = min(max(y0 - 1 + ly, 0), H2 - 1);
        long q = base + (long)yy * W2 + xx;
        float rh, rv, rd, ah, av, ad;
        decouple6(POh[q], POv[q], POd[q], PTh[q], PTv[q], PTd[q],
                  rh, rv, rd, ah, av, ad);
        sh[ly][lx] = fabsf(rfh * ah);
        sv[ly][lx] = fabsf(rfv * av);
        sd[ly][lx] = fabsf(rfd * ad);
        srh[ly][lx] = rh;
        srv[ly][lx] = rv;
        srd[ly][lx] = rd;
    }
    __syncthreads();

    int x = x0 + threadIdx.x, y = y0 + threadIdx.y;
    float denh = 0.f, denv = 0.f, dend = 0.f;
    float numh = 0.f, numv = 0.f, numd = 0.f;

    if (x < right && y < bottom) {
        long o = base + (long)y * W2 + x;
        float oh = POh[o], ov = POv[o], od = POd[o];
        float t;
        t = fabsf(rfh * oh); denh = t * t * t;
        t = fabsf(rfv * ov); denv = t * t * t;
        t = fabsf(rfd * od); dend = t * t * t;

        int lx = threadIdx.x + 1, ly = threadIdx.y + 1;
        const float w0 = 1.f / 30.f, wc = 1.f / 15.f;
        float thrh = wc * sh[ly][lx] + w0 * (sh[ly - 1][lx - 1] + sh[ly - 1][lx] + sh[ly - 1][lx + 1] +
                                             sh[ly][lx - 1] + sh[ly][lx + 1] +
                                             sh[ly + 1][lx - 1] + sh[ly + 1][lx] + sh[ly + 1][lx + 1]);
        float thrv = wc * sv[ly][lx] + w0 * (sv[ly - 1][lx - 1] + sv[ly - 1][lx] + sv[ly - 1][lx + 1] +
                                             sv[ly][lx - 1] + sv[ly][lx + 1] +
                                             sv[ly + 1][lx - 1] + sv[ly + 1][lx] + sv[ly + 1][lx + 1]);
        float thrd = wc * sd[ly][lx] + w0 * (sd[ly - 1][lx - 1] + sd[ly - 1][lx] + sd[ly - 1][lx + 1] +
                                             sd[ly][lx - 1] + sd[ly][lx + 1] +
                                             sd[ly + 1][lx - 1] + sd[ly + 1][lx] + sd[ly + 1][lx + 1]);

        t = fmaxf(fabsf(rfh * srh[ly][lx]) - thrh, 0.f); numh = t * t * t;
        t = fmaxf(fabsf(rfv * srv[ly][lx]) - thrv, 0.f); numv = t * t * t;
        t = fmaxf(fabsf(rfd * srd[ly][lx]) - thrd, 0.f); numd = t * t * t;
    }

    // block reduction: 256 threads = 4 waves
    float vals[6] = {denh, denv, dend, numh, numv, numd};
    #pragma unroll
    for (int i = 0; i < 6; ++i) {
        float v = vals[i];
        #pragma unroll
        for (int off = 32; off > 0; off >>= 1) v += __shfl_down(v, off, 64);
        vals[i] = v;
    }
    __shared__ float smem[4][6];
    __syncthreads();
    if ((tid & 63) == 0) {
        #pragma unroll
        for (int i = 0; i < 6; ++i) smem[tid >> 6][i] = vals[i];
    }
    __syncthreads();
    if (tid < 6) {
        float s = smem[0][tid] + smem[1][tid] + smem[2][tid] + smem[3][tid];
        atomicAdd(&acc[((long)b * 4 + scale) * 6 + tid], s);
    }
}

__global__ void zero_kernel(float* __restrict__ acc)
{
    int i = threadIdx.x;
    if (i < BATCH * 4 * 6) acc[i] = 0.f;
}

__global__ void final_kernel(const float* __restrict__ acc, float* __restrict__ out,
                             float c0, float c1, float c2, float c3)
{
    int b = threadIdx.x;
    if (b >= BATCH) return;
    float cs[4] = {c0, c1, c2, c3};
    float num = 0.f, den = 0.f;
    for (int s = 0; s < 4; ++s) {
        const float* a = acc + ((long)b * 4 + s) * 6;
        den += cbrtf(a[0]) + cbrtf(a[1]) + cbrtf(a[2]) + cs[s];
        num += cbrtf(a[3]) + cbrtf(a[4]) + cbrtf(a[5]) + cs[s];
    }
    const float lim = 1e-10f;
    if (num < lim) num = 0.f;
    if (den < lim) den = 0.f;
    out[b] = (den == 0.f) ? 1.f : num / den;
}

// --------------------------------------------------------------------------
extern "C" void kernel_launch(void* const* d_in, const int* in_sizes, int n_in,
                              void* d_out, int out_size, void* d_ws, size_t ws_size,
                              hipStream_t stream)
{
    const float* Xref = (const float*)d_in[0];
    const float* Xdst = (const float*)d_in[1];
    float* out = (float*)d_out;
    float* ws  = (float*)d_ws;

    float* aRefA = ws + (long)0 * BATCH * S0;
    float* aRefB = ws + (long)1 * BATCH * S0;
    float* aDstA = ws + (long)2 * BATCH * S0;
    float* aDstB = ws + (long)3 * BATCH * S0;
    float* Oh    = ws + (long)4 * BATCH * S0;
    float* Ov    = ws + (long)5 * BATCH * S0;
    float* Od    = ws + (long)6 * BATCH * S0;
    float* Th    = ws + (long)7 * BATCH * S0;
    float* Tv    = ws + (long)8 * BATCH * S0;
    float* Td    = ws + (long)9 * BATCH * S0;
    float* acc   = ws + (long)10 * BATCH * S0;

    zero_kernel<<<dim3(1), dim3(128), 0, stream>>>(acc);

    static const float RF[4][3] = {
        {0.017382f, 0.017382f, 0.005891f},
        {0.031985f, 0.031985f, 0.014299f},
        {0.043373f, 0.043373f, 0.024397f},
        {0.045673f, 0.045673f, 0.031313f}};

    int H = 1080, W = 1920;
    long srcStride = (long)H * W;
    const float* sR = Xref;
    const float* sD = Xdst;
    float* pingR[2] = {aRefA, aRefB};
    float* pingD[2] = {aDstA, aDstB};
    float cs[4];

    for (int s = 0; s < 4; ++s) {
        int H2 = (H + 1) / 2, W2 = (W + 1) / 2;
        float* oR = pingR[s & 1];
        float* oD = pingD[s & 1];

        dim3 blk(64, 4), grd((W2 + 63) / 64, (H2 + 3) / 4, BATCH);
        dwt_kernel<<<grd, blk, 0, stream>>>(sR, srcStride, H, W, oR, Oh, Ov, Od, H2, W2);
        dwt_kernel<<<grd, blk, 0, stream>>>(sD, srcStride, H, W, oD, Th, Tv, Td, H2, W2);

        int left   = (int)floor((double)W2 * 0.1 - 0.5);
        int top    = (int)floor((double)H2 * 0.1 - 0.5);
        int right  = W2 - left;
        int bottom = H2 - top;
        int Wi = right - left, Hi = bottom - top;

        dim3 rblk(RBX, RBY), rgrd((Wi + RBX - 1) / RBX, (Hi + RBY - 1) / RBY, BATCH);
        reduce_kernel<<<rgrd, rblk, 0, stream>>>(Oh, Ov, Od, Th, Tv, Td,
                                                 H2, W2, left, top, right, bottom,
                                                 RF[s][0], RF[s][1], RF[s][2], acc, s);

        cs[s] = 3.0f * cbrtf((float)((long)(bottom - top) * (right - left)) / 32.0f);

        sR = oR; sD = oD; srcStride = S0;
        H = H2; W = W2;
    }

    final_kernel<<<dim3(1), dim3(64), 0, stream>>>(acc, out, cs[0], cs[1], cs[2], cs[3]);
}

// Round 3
// 87.679 us; speedup vs baseline: 2.0733x; 1.6821x over previous
//
#include <hip/hip_runtime.h>
#include <math.h>

#define BATCH 4
#define S0 (540 * 960)
#define REPL 32

#define FBX 32
#define FBY 8
#define HTW 34          // halo tile width  (FBX + 2)
#define HTH 10          // halo tile height (FBY + 2)
#define HTP 35          // padded LDS stride (odd)
#define SRW 70          // source tile cols (2*HTW + 2)
#define SRH 22          // source tile rows (2*HTH + 2)
#define SRP 71          // padded LDS stride (odd)

__device__ __forceinline__ int reflect_idx(int i, int n) {
    if (i < 0) i = -i;
    if (i >= n) i = 2 * n - 2 - i;
    return i;
}

__device__ __forceinline__ void decouple6(float oh, float ov, float od,
                                          float th, float tv, float td,
                                          float& Rh, float& Rv, float& Rd,
                                          float& Ah, float& Av, float& Ad)
{
    const float EPS = 1e-30f;
    const float COS1SQ = 0.9996954135095479f;

    float kh = th / (oh + EPS); kh = fminf(fmaxf(kh, 0.f), 1.f);
    float kv = tv / (ov + EPS); kv = fminf(fmaxf(kv, 0.f), 1.f);
    float kd = td / (od + EPS); kd = fminf(fmaxf(kd, 0.f), 1.f);
    float rh = kh * oh, rv = kv * ov, rd = kd * od;

    float ot = oh * th + ov * tv;
    bool flag = (ot >= 0.f) &&
                (ot * ot >= COS1SQ * (oh * oh + ov * ov) * (th * th + tv * tv));
    if (flag) {
        if (rh > 0.f) rh = fminf(rh * 100.f, th);
        if (rh < 0.f) rh = fmaxf(rh * 100.f, th);
        if (rv > 0.f) rv = fminf(rv * 100.f, tv);
        if (rv < 0.f) rv = fmaxf(rv * 100.f, tv);
        if (rd > 0.f) rd = fminf(rd * 100.f, td);
        if (rd < 0.f) rd = fmaxf(rd * 100.f, td);
    }
    Rh = rh; Rv = rv; Rd = rd;
    Ah = th - rh; Av = tv - rv; Ad = td - rd;
}

// --------------------------------------------------------------------------
// Fused per-scale kernel: DWT(ref) + DWT(dst) + decouple + den/num reduce.
// Writes only the approx bands to global; h/v/d live in LDS only.
// acc layout: [REPL][BATCH][4 scales][6] = {den_h,den_v,den_d,num_h,num_v,num_d}
// --------------------------------------------------------------------------
__global__ __launch_bounds__(256) void
fused_kernel(const float* __restrict__ srcR, const float* __restrict__ srcD,
             long srcBatchStride, int H, int W, int H2, int W2,
             float* __restrict__ outAR, float* __restrict__ outAD,
             int left, int top, int right, int bottom,
             float rfh, float rfv, float rfd,
             float* __restrict__ acc, int scale)
{
    const float LO0 =  0.48296291314469f,  LO1 =  0.836516303737469f,
                LO2 =  0.224143868041857f, LO3 = -0.129409522550921f;
    const float HI0 = -0.129409522550921f, HI1 = -0.224143868041857f,
                HI2 =  0.836516303737469f, HI3 = -0.48296291314469f;

    __shared__ float sRf[SRH][SRP], sDt[SRH][SRP];
    __shared__ float sh[HTH][HTP], sv[HTH][HTP], sd[HTH][HTP];
    __shared__ float srh[HTH][HTP], srv[HTH][HTP], srd[HTH][HTP];

    int b  = blockIdx.z;
    int x0 = blockIdx.x * FBX;
    int y0 = blockIdx.y * FBY;
    int tid = threadIdx.y * FBX + threadIdx.x;

    const float* pR = srcR + (long)b * srcBatchStride;
    const float* pD = srcD + (long)b * srcBatchStride;

    // ---- stage reflected source tiles for both images ----
    for (int i = tid; i < SRW * SRH; i += 256) {
        int c = i % SRW, r = i / SRW;
        int gr = reflect_idx(2 * y0 - 3 + r, H);
        int gc = reflect_idx(2 * x0 - 3 + c, W);
        long q = (long)gr * W + gc;
        sRf[r][c] = pR[q];
        sDt[r][c] = pD[q];
    }
    __syncthreads();

    float denh = 0.f, denv = 0.f, dend = 0.f;
    float numh = 0.f, numv = 0.f, numd = 0.f;
    long base2 = (long)b * S0;

    // ---- halo DWT (both images) + decouple + den + approx write ----
    for (int i = tid; i < HTW * HTH; i += 256) {
        int lx = i % HTW, ly = i / HTW;

        float vloR[4], vhiR[4], vloD[4], vhiD[4];
        #pragma unroll
        for (int l = 0; l < 4; ++l) {
            int cc = 2 * lx + l;
            float r0 = sRf[2 * ly + 0][cc], r1 = sRf[2 * ly + 1][cc],
                  r2 = sRf[2 * ly + 2][cc], r3 = sRf[2 * ly + 3][cc];
            vloR[l] = LO0 * r0 + LO1 * r1 + LO2 * r2 + LO3 * r3;
            vhiR[l] = HI0 * r0 + HI1 * r1 + HI2 * r2 + HI3 * r3;
            float d0 = sDt[2 * ly + 0][cc], d1 = sDt[2 * ly + 1][cc],
                  d2 = sDt[2 * ly + 2][cc], d3 = sDt[2 * ly + 3][cc];
            vloD[l] = LO0 * d0 + LO1 * d1 + LO2 * d2 + LO3 * d3;
            vhiD[l] = HI0 * d0 + HI1 * d1 + HI2 * d2 + HI3 * d3;
        }
        float aR = LO0 * vloR[0] + LO1 * vloR[1] + LO2 * vloR[2] + LO3 * vloR[3];
        float oh = LO0 * vhiR[0] + LO1 * vhiR[1] + LO2 * vhiR[2] + LO3 * vhiR[3];
        float ov = HI0 * vloR[0] + HI1 * vloR[1] + HI2 * vloR[2] + HI3 * vloR[3];
        float od = HI0 * vhiR[0] + HI1 * vhiR[1] + HI2 * vhiR[2] + HI3 * vhiR[3];
        float aD = LO0 * vloD[0] + LO1 * vloD[1] + LO2 * vloD[2] + LO3 * vloD[3];
        float th = LO0 * vhiD[0] + LO1 * vhiD[1] + LO2 * vhiD[2] + LO3 * vhiD[3];
        float tv = HI0 * vloD[0] + HI1 * vloD[1] + HI2 * vloD[2] + HI3 * vloD[3];
        float td = HI0 * vhiD[0] + HI1 * vhiD[1] + HI2 * vhiD[2] + HI3 * vhiD[3];

        float rh, rv, rd, ah, av, ad;
        decouple6(oh, ov, od, th, tv, td, rh, rv, rd, ah, av, ad);
        sh[ly][lx]  = fabsf(rfh * ah);
        sv[ly][lx]  = fabsf(rfv * av);
        sd[ly][lx]  = fabsf(rfd * ad);
        srh[ly][lx] = rh;
        srv[ly][lx] = rv;
        srd[ly][lx] = rd;

        int bx = x0 - 1 + lx, by = y0 - 1 + ly;
        bool center = (lx >= 1) && (lx <= FBX) && (ly >= 1) && (ly <= FBY);
        if (center && bx < W2 && by < H2) {
            long o = base2 + (long)by * W2 + bx;
            outAR[o] = aR;
            outAD[o] = aD;
            if (bx >= left && bx < right && by >= top && by < bottom) {
                float t;
                t = fabsf(rfh * oh); denh += t * t * t;
                t = fabsf(rfv * ov); denv += t * t * t;
                t = fabsf(rfd * od); dend += t * t * t;
            }
        }
    }
    __syncthreads();

    // ---- num pass: 3x3 CM conv from LDS ----
    {
        int bx = x0 + threadIdx.x, by = y0 + threadIdx.y;
        if (bx >= left && bx < right && by >= top && by < bottom) {
            int lx = threadIdx.x + 1, ly = threadIdx.y + 1;
            const float w0 = 1.f / 30.f, wc = 1.f / 15.f;
            float thrh = wc * sh[ly][lx] + w0 * (sh[ly-1][lx-1] + sh[ly-1][lx] + sh[ly-1][lx+1] +
                                                 sh[ly][lx-1]   + sh[ly][lx+1] +
                                                 sh[ly+1][lx-1] + sh[ly+1][lx] + sh[ly+1][lx+1]);
            float thrv = wc * sv[ly][lx] + w0 * (sv[ly-1][lx-1] + sv[ly-1][lx] + sv[ly-1][lx+1] +
                                                 sv[ly][lx-1]   + sv[ly][lx+1] +
                                                 sv[ly+1][lx-1] + sv[ly+1][lx] + sv[ly+1][lx+1]);
            float thrd = wc * sd[ly][lx] + w0 * (sd[ly-1][lx-1] + sd[ly-1][lx] + sd[ly-1][lx+1] +
                                                 sd[ly][lx-1]   + sd[ly][lx+1] +
                                                 sd[ly+1][lx-1] + sd[ly+1][lx] + sd[ly+1][lx+1]);
            float t;
            t = fmaxf(fabsf(rfh * srh[ly][lx]) - thrh, 0.f); numh = t * t * t;
            t = fmaxf(fabsf(rfv * srv[ly][lx]) - thrv, 0.f); numv = t * t * t;
            t = fmaxf(fabsf(rfd * srd[ly][lx]) - thrd, 0.f); numd = t * t * t;
        }
    }

    // ---- block reduce (256 threads = 4 waves) ----
    float vals[6] = {denh, denv, dend, numh, numv, numd};
    #pragma unroll
    for (int i = 0; i < 6; ++i) {
        float v = vals[i];
        #pragma unroll
        for (int off = 32; off > 0; off >>= 1) v += __shfl_down(v, off, 64);
        vals[i] = v;
    }
    __shared__ float smem[4][6];
    __syncthreads();
    if ((tid & 63) == 0) {
        #pragma unroll
        for (int i = 0; i < 6; ++i) smem[tid >> 6][i] = vals[i];
    }
    __syncthreads();
    if (tid < 6) {
        float s = smem[0][tid] + smem[1][tid] + smem[2][tid] + smem[3][tid];
        int repl = (blockIdx.y * gridDim.x + blockIdx.x) % REPL;
        atomicAdd(&acc[(((long)repl * BATCH + b) * 4 + scale) * 6 + tid], s);
    }
}

__global__ void zero_kernel(float* __restrict__ acc)
{
    int i = blockIdx.x * blockDim.x + threadIdx.x;
    if (i < REPL * BATCH * 4 * 6) acc[i] = 0.f;
}

__global__ void final_kernel(const float* __restrict__ acc, float* __restrict__ out,
                             float c0, float c1, float c2, float c3)
{
    __shared__ float tot[BATCH][4][6];
    int t = threadIdx.x;
    if (t < BATCH * 4 * 6) {
        int k = t % 6, s = (t / 6) % 4, b = t / 24;
        float v = 0.f;
        for (int r = 0; r < REPL; ++r)
            v += acc[(((long)r * BATCH + b) * 4 + s) * 6 + k];
        tot[b][s][k] = v;
    }
    __syncthreads();
    if (t < BATCH) {
        float cs[4] = {c0, c1, c2, c3};
        float num = 0.f, den = 0.f;
        for (int s = 0; s < 4; ++s) {
            den += cbrtf(tot[t][s][0]) + cbrtf(tot[t][s][1]) + cbrtf(tot[t][s][2]) + cs[s];
            num += cbrtf(tot[t][s][3]) + cbrtf(tot[t][s][4]) + cbrtf(tot[t][s][5]) + cs[s];
        }
        const float lim = 1e-10f;
        if (num < lim) num = 0.f;
        if (den < lim) den = 0.f;
        out[t] = (den == 0.f) ? 1.f : num / den;
    }
}

// --------------------------------------------------------------------------
extern "C" void kernel_launch(void* const* d_in, const int* in_sizes, int n_in,
                              void* d_out, int out_size, void* d_ws, size_t ws_size,
                              hipStream_t stream)
{
    const float* Xref = (const float*)d_in[0];
    const float* Xdst = (const float*)d_in[1];
    float* out = (float*)d_out;
    float* ws  = (float*)d_ws;

    float* aRefA = ws + (long)0 * BATCH * S0;
    float* aRefB = ws + (long)1 * BATCH * S0;
    float* aDstA = ws + (long)2 * BATCH * S0;
    float* aDstB = ws + (long)3 * BATCH * S0;
    float* acc   = ws + (long)4 * BATCH * S0;

    zero_kernel<<<dim3((REPL * BATCH * 24 + 255) / 256), dim3(256), 0, stream>>>(acc);

    static const float RF[4][3] = {
        {0.017382f, 0.017382f, 0.005891f},
        {0.031985f, 0.031985f, 0.014299f},
        {0.043373f, 0.043373f, 0.024397f},
        {0.045673f, 0.045673f, 0.031313f}};

    int H = 1080, W = 1920;
    long srcStride = (long)H * W;
    const float* sR = Xref;
    const float* sD = Xdst;
    float* pingR[2] = {aRefA, aRefB};
    float* pingD[2] = {aDstA, aDstB};
    float cs[4];

    for (int s = 0; s < 4; ++s) {
        int H2 = (H + 1) / 2, W2 = (W + 1) / 2;
        float* oR = pingR[s & 1];
        float* oD = pingD[s & 1];

        int left   = (int)floor((double)W2 * 0.1 - 0.5);
        int top    = (int)floor((double)H2 * 0.1 - 0.5);
        int right  = W2 - left;
        int bottom = H2 - top;

        dim3 blk(FBX, FBY), grd((W2 + FBX - 1) / FBX, (H2 + FBY - 1) / FBY, BATCH);
        fused_kernel<<<grd, blk, 0, stream>>>(sR, sD, srcStride, H, W, H2, W2,
                                              oR, oD, left, top, right, bottom,
                                              RF[s][0], RF[s][1], RF[s][2], acc, s);

        cs[s] = 3.0f * cbrtf((float)((long)(bottom - top) * (right - left)) / 32.0f);

        sR = oR; sD = oD; srcStride = S0;
        H = H2; W = W2;
    }

    final_kernel<<<dim3(1), dim3(128), 0, stream>>>(acc, out, cs[0], cs[1], cs[2], cs[3]);
}

// Round 4
// 73.149 us; speedup vs baseline: 2.4852x; 1.1986x over previous
//
#include <hip/hip_runtime.h>
#include <math.h>

#define BATCH 4
#define S0 (540 * 960)
#define REPL 32

#define FBX 32
#define FBY 16
#define NTHR 512
#define HTW 34          // halo positions per row (FBX + 2)
#define HTH 18          // halo position rows    (FBY + 2)
#define HTP 36          // padded LDS stride for band tiles
#define SRW 70          // source cols per tile (2*HTW + 2)
#define VP  72          // padded LDS stride for vertical-filter tiles

__device__ __forceinline__ int reflect_idx(int i, int n) {
    if (i < 0) i = -i;
    if (i >= n) i = 2 * n - 2 - i;
    return i;
}

__device__ __forceinline__ void decouple6(float oh, float ov, float od,
                                          float th, float tv, float td,
                                          float& Rh, float& Rv, float& Rd,
                                          float& Ah, float& Av, float& Ad)
{
    const float EPS = 1e-30f;
    const float COS1SQ = 0.9996954135095479f;

    float kh = th / (oh + EPS); kh = fminf(fmaxf(kh, 0.f), 1.f);
    float kv = tv / (ov + EPS); kv = fminf(fmaxf(kv, 0.f), 1.f);
    float kd = td / (od + EPS); kd = fminf(fmaxf(kd, 0.f), 1.f);
    float rh = kh * oh, rv = kv * ov, rd = kd * od;

    float ot = oh * th + ov * tv;
    bool flag = (ot >= 0.f) &&
                (ot * ot >= COS1SQ * (oh * oh + ov * ov) * (th * th + tv * tv));
    if (flag) {
        if (rh > 0.f) rh = fminf(rh * 100.f, th);
        if (rh < 0.f) rh = fmaxf(rh * 100.f, th);
        if (rv > 0.f) rv = fminf(rv * 100.f, tv);
        if (rv < 0.f) rv = fmaxf(rv * 100.f, tv);
        if (rd > 0.f) rd = fminf(rd * 100.f, td);
        if (rd < 0.f) rd = fmaxf(rd * 100.f, td);
    }
    Rh = rh; Rv = rv; Rd = rd;
    Ah = th - rh; Av = tv - rv; Ad = td - rd;
}

// --------------------------------------------------------------------------
// Fused per-scale kernel, separable DWT:
//   A: vertical filter (global -> LDS vlo/vhi), each column result once
//   B: horizontal filter (LDS -> bands) + decouple + den + approx write
//   C: 3x3 CM conv (LDS) -> num;  block reduce -> atomics
// acc layout: [REPL][BATCH][4][6] = {den_h,den_v,den_d,num_h,num_v,num_d}
// --------------------------------------------------------------------------
__global__ __launch_bounds__(NTHR) void
fused_kernel(const float* __restrict__ srcR, const float* __restrict__ srcD,
             long srcBatchStride, int H, int W, int H2, int W2,
             float* __restrict__ outAR, float* __restrict__ outAD,
             int left, int top, int right, int bottom,
             float rfh, float rfv, float rfd,
             float* __restrict__ acc, int scale)
{
    const float LO0 =  0.48296291314469f,  LO1 =  0.836516303737469f,
                LO2 =  0.224143868041857f, LO3 = -0.129409522550921f;
    const float HI0 = -0.129409522550921f, HI1 = -0.224143868041857f,
                HI2 =  0.836516303737469f, HI3 = -0.48296291314469f;

    __shared__ float sVloR[HTH][VP], sVhiR[HTH][VP];
    __shared__ float sVloD[HTH][VP], sVhiD[HTH][VP];
    __shared__ float sh[HTH][HTP], sv[HTH][HTP], sd[HTH][HTP];
    __shared__ float srh[HTH][HTP], srv[HTH][HTP], srd[HTH][HTP];
    __shared__ float smem[8][6];

    int b  = blockIdx.z;
    int X0 = blockIdx.x * FBX;
    int Y0 = blockIdx.y * FBY;
    int tid = threadIdx.y * FBX + threadIdx.x;

    const float* pR = srcR + (long)b * srcBatchStride;
    const float* pD = srcD + (long)b * srcBatchStride;

    // ---- Phase A: vertical db2 filter, both images, addresses reused ----
    for (int i = tid; i < SRW * HTH; i += NTHR) {
        int c = i % SRW, ly = i / SRW;
        int gc = reflect_idx(2 * X0 - 3 + c, W);
        int rb = 2 * Y0 + 2 * ly - 3;
        long q0 = (long)reflect_idx(rb + 0, H) * W + gc;
        long q1 = (long)reflect_idx(rb + 1, H) * W + gc;
        long q2 = (long)reflect_idx(rb + 2, H) * W + gc;
        long q3 = (long)reflect_idx(rb + 3, H) * W + gc;
        float r0 = pR[q0], r1 = pR[q1], r2 = pR[q2], r3 = pR[q3];
        sVloR[ly][c] = LO0 * r0 + LO1 * r1 + LO2 * r2 + LO3 * r3;
        sVhiR[ly][c] = HI0 * r0 + HI1 * r1 + HI2 * r2 + HI3 * r3;
        float d0 = pD[q0], d1 = pD[q1], d2 = pD[q2], d3 = pD[q3];
        sVloD[ly][c] = LO0 * d0 + LO1 * d1 + LO2 * d2 + LO3 * d3;
        sVhiD[ly][c] = HI0 * d0 + HI1 * d1 + HI2 * d2 + HI3 * d3;
    }
    __syncthreads();

    float denh = 0.f, denv = 0.f, dend = 0.f;
    float numh = 0.f, numv = 0.f, numd = 0.f;
    long base2 = (long)b * S0;

    // ---- Phase B: horizontal filter + decouple + den + approx write ----
    for (int i = tid; i < HTW * HTH; i += NTHR) {
        int lx = i % HTW, ly = i / HTW;
        int cc = 2 * lx;

        float l0 = sVloR[ly][cc], l1 = sVloR[ly][cc + 1],
              l2 = sVloR[ly][cc + 2], l3 = sVloR[ly][cc + 3];
        float h0 = sVhiR[ly][cc], h1 = sVhiR[ly][cc + 1],
              h2 = sVhiR[ly][cc + 2], h3 = sVhiR[ly][cc + 3];
        float aR = LO0 * l0 + LO1 * l1 + LO2 * l2 + LO3 * l3;
        float ov = HI0 * l0 + HI1 * l1 + HI2 * l2 + HI3 * l3;
        float oh = LO0 * h0 + LO1 * h1 + LO2 * h2 + LO3 * h3;
        float od = HI0 * h0 + HI1 * h1 + HI2 * h2 + HI3 * h3;

        l0 = sVloD[ly][cc]; l1 = sVloD[ly][cc + 1];
        l2 = sVloD[ly][cc + 2]; l3 = sVloD[ly][cc + 3];
        h0 = sVhiD[ly][cc]; h1 = sVhiD[ly][cc + 1];
        h2 = sVhiD[ly][cc + 2]; h3 = sVhiD[ly][cc + 3];
        float aD = LO0 * l0 + LO1 * l1 + LO2 * l2 + LO3 * l3;
        float tv = HI0 * l0 + HI1 * l1 + HI2 * l2 + HI3 * l3;
        float th = LO0 * h0 + LO1 * h1 + LO2 * h2 + LO3 * h3;
        float td = HI0 * h0 + HI1 * h1 + HI2 * h2 + HI3 * h3;

        float rh, rv, rd, ah, av, ad;
        decouple6(oh, ov, od, th, tv, td, rh, rv, rd, ah, av, ad);
        sh[ly][lx]  = fabsf(rfh * ah);
        sv[ly][lx]  = fabsf(rfv * av);
        sd[ly][lx]  = fabsf(rfd * ad);
        srh[ly][lx] = rh;
        srv[ly][lx] = rv;
        srd[ly][lx] = rd;

        int bx = X0 - 1 + lx, by = Y0 - 1 + ly;
        bool center = (lx >= 1) && (lx <= FBX) && (ly >= 1) && (ly <= FBY);
        if (center && bx < W2 && by < H2) {
            long o = base2 + (long)by * W2 + bx;
            outAR[o] = aR;
            outAD[o] = aD;
            if (bx >= left && bx < right && by >= top && by < bottom) {
                float t;
                t = fabsf(rfh * oh); denh += t * t * t;
                t = fabsf(rfv * ov); denv += t * t * t;
                t = fabsf(rfd * od); dend += t * t * t;
            }
        }
    }
    __syncthreads();

    // ---- Phase C: 3x3 CM conv -> num ----
    {
        int bx = X0 + threadIdx.x, by = Y0 + threadIdx.y;
        if (bx >= left && bx < right && by >= top && by < bottom) {
            int lx = threadIdx.x + 1, ly = threadIdx.y + 1;
            const float w0 = 1.f / 30.f, wc = 1.f / 15.f;
            float thrh = wc * sh[ly][lx] + w0 * (sh[ly-1][lx-1] + sh[ly-1][lx] + sh[ly-1][lx+1] +
                                                 sh[ly][lx-1]   + sh[ly][lx+1] +
                                                 sh[ly+1][lx-1] + sh[ly+1][lx] + sh[ly+1][lx+1]);
            float thrv = wc * sv[ly][lx] + w0 * (sv[ly-1][lx-1] + sv[ly-1][lx] + sv[ly-1][lx+1] +
                                                 sv[ly][lx-1]   + sv[ly][lx+1] +
                                                 sv[ly+1][lx-1] + sv[ly+1][lx] + sv[ly+1][lx+1]);
            float thrd = wc * sd[ly][lx] + w0 * (sd[ly-1][lx-1] + sd[ly-1][lx] + sd[ly-1][lx+1] +
                                                 sd[ly][lx-1]   + sd[ly][lx+1] +
                                                 sd[ly+1][lx-1] + sd[ly+1][lx] + sd[ly+1][lx+1]);
            float t;
            t = fmaxf(fabsf(rfh * srh[ly][lx]) - thrh, 0.f); numh = t * t * t;
            t = fmaxf(fabsf(rfv * srv[ly][lx]) - thrv, 0.f); numv = t * t * t;
            t = fmaxf(fabsf(rfd * srd[ly][lx]) - thrd, 0.f); numd = t * t * t;
        }
    }

    // ---- block reduce (512 threads = 8 waves) ----
    float vals[6] = {denh, denv, dend, numh, numv, numd};
    #pragma unroll
    for (int i = 0; i < 6; ++i) {
        float v = vals[i];
        #pragma unroll
        for (int off = 32; off > 0; off >>= 1) v += __shfl_down(v, off, 64);
        vals[i] = v;
    }
    __syncthreads();
    if ((tid & 63) == 0) {
        #pragma unroll
        for (int i = 0; i < 6; ++i) smem[tid >> 6][i] = vals[i];
    }
    __syncthreads();
    if (tid < 6) {
        float s = 0.f;
        #pragma unroll
        for (int w = 0; w < 8; ++w) s += smem[w][tid];
        int repl = (blockIdx.y * gridDim.x + blockIdx.x) % REPL;
        atomicAdd(&acc[(((long)repl * BATCH + b) * 4 + scale) * 6 + tid], s);
    }
}

__global__ void zero_kernel(float* __restrict__ acc)
{
    int i = blockIdx.x * blockDim.x + threadIdx.x;
    if (i < REPL * BATCH * 4 * 6) acc[i] = 0.f;
}

__global__ void final_kernel(const float* __restrict__ acc, float* __restrict__ out,
                             float c0, float c1, float c2, float c3)
{
    __shared__ float tot[BATCH][4][6];
    int t = threadIdx.x;
    if (t < BATCH * 4 * 6) {
        int k = t % 6, s = (t / 6) % 4, b = t / 24;
        float v = 0.f;
        for (int r = 0; r < REPL; ++r)
            v += acc[(((long)r * BATCH + b) * 4 + s) * 6 + k];
        tot[b][s][k] = v;
    }
    __syncthreads();
    if (t < BATCH) {
        float cs[4] = {c0, c1, c2, c3};
        float num = 0.f, den = 0.f;
        for (int s = 0; s < 4; ++s) {
            den += cbrtf(tot[t][s][0]) + cbrtf(tot[t][s][1]) + cbrtf(tot[t][s][2]) + cs[s];
            num += cbrtf(tot[t][s][3]) + cbrtf(tot[t][s][4]) + cbrtf(tot[t][s][5]) + cs[s];
        }
        const float lim = 1e-10f;
        if (num < lim) num = 0.f;
        if (den < lim) den = 0.f;
        out[t] = (den == 0.f) ? 1.f : num / den;
    }
}

// --------------------------------------------------------------------------
extern "C" void kernel_launch(void* const* d_in, const int* in_sizes, int n_in,
                              void* d_out, int out_size, void* d_ws, size_t ws_size,
                              hipStream_t stream)
{
    const float* Xref = (const float*)d_in[0];
    const float* Xdst = (const float*)d_in[1];
    float* out = (float*)d_out;
    float* ws  = (float*)d_ws;

    float* aRefA = ws + (long)0 * BATCH * S0;
    float* aRefB = ws + (long)1 * BATCH * S0;
    float* aDstA = ws + (long)2 * BATCH * S0;
    float* aDstB = ws + (long)3 * BATCH * S0;
    float* acc   = ws + (long)4 * BATCH * S0;

    zero_kernel<<<dim3((REPL * BATCH * 24 + 255) / 256), dim3(256), 0, stream>>>(acc);

    static const float RF[4][3] = {
        {0.017382f, 0.017382f, 0.005891f},
        {0.031985f, 0.031985f, 0.014299f},
        {0.043373f, 0.043373f, 0.024397f},
        {0.045673f, 0.045673f, 0.031313f}};

    int H = 1080, W = 1920;
    long srcStride = (long)H * W;
    const float* sR = Xref;
    const float* sD = Xdst;
    float* pingR[2] = {aRefA, aRefB};
    float* pingD[2] = {aDstA, aDstB};
    float cs[4];

    for (int s = 0; s < 4; ++s) {
        int H2 = (H + 1) / 2, W2 = (W + 1) / 2;
        float* oR = pingR[s & 1];
        float* oD = pingD[s & 1];

        int left   = (int)floor((double)W2 * 0.1 - 0.5);
        int top    = (int)floor((double)H2 * 0.1 - 0.5);
        int right  = W2 - left;
        int bottom = H2 - top;

        dim3 blk(FBX, FBY), grd((W2 + FBX - 1) / FBX, (H2 + FBY - 1) / FBY, BATCH);
        fused_kernel<<<grd, blk, 0, stream>>>(sR, sD, srcStride, H, W, H2, W2,
                                              oR, oD, left, top, right, bottom,
                                              RF[s][0], RF[s][1], RF[s][2], acc, s);

        cs[s] = 3.0f * cbrtf((float)((long)(bottom - top) * (right - left)) / 32.0f);

        sR = oR; sD = oD; srcStride = S0;
        H = H2; W = W2;
    }

    final_kernel<<<dim3(1), dim3(128), 0, stream>>>(acc, out, cs[0], cs[1], cs[2], cs[3]);
}

// Round 5
// 68.421 us; speedup vs baseline: 2.6569x; 1.0691x over previous
//
#include <hip/hip_runtime.h>
#include <math.h>

#define BATCH 4
#define S0 (540 * 960)
#define REPL 32

#define FBX 32
#define FBY 16
#define NTHR 512
#define HTW 34          // halo positions per row (FBX + 2)
#define HTH 18          // halo position rows    (FBY + 2)
#define HTP 35          // padded LDS stride for float2 band tiles
#define SRW 70          // source tile cols (2*HTW + 2)
#define VP  72          // padded LDS stride for vertical-filter tiles

__device__ __forceinline__ int reflect_idx(int i, int n) {
    if (i < 0) i = -i;
    if (i >= n) i = 2 * n - 2 - i;
    return i;
}

__device__ __forceinline__ void decouple6(float oh, float ov, float od,
                                          float th, float tv, float td,
                                          float& Rh, float& Rv, float& Rd,
                                          float& Ah, float& Av, float& Ad)
{
    const float EPS = 1e-30f;
    const float COS1SQ = 0.9996954135095479f;

    float kh = th / (oh + EPS); kh = fminf(fmaxf(kh, 0.f), 1.f);
    float kv = tv / (ov + EPS); kv = fminf(fmaxf(kv, 0.f), 1.f);
    float kd = td / (od + EPS); kd = fminf(fmaxf(kd, 0.f), 1.f);
    float rh = kh * oh, rv = kv * ov, rd = kd * od;

    float ot = oh * th + ov * tv;
    bool flag = (ot >= 0.f) &&
                (ot * ot >= COS1SQ * (oh * oh + ov * ov) * (th * th + tv * tv));
    if (flag) {
        if (rh > 0.f) rh = fminf(rh * 100.f, th);
        if (rh < 0.f) rh = fmaxf(rh * 100.f, th);
        if (rv > 0.f) rv = fminf(rv * 100.f, tv);
        if (rv < 0.f) rv = fmaxf(rv * 100.f, tv);
        if (rd > 0.f) rd = fminf(rd * 100.f, td);
        if (rd < 0.f) rd = fmaxf(rd * 100.f, td);
    }
    Rh = rh; Rv = rv; Rd = rd;
    Ah = th - rh; Av = tv - rv; Ad = td - rd;
}

// --------------------------------------------------------------------------
// Fused per-scale kernel, separable DWT:
//   A: vertical filter (global -> LDS vlo/vhi), ROW-PAIRED (6 loads / 2 rows),
//      block-uniform interior fast path (no reflect)
//   B: horizontal filter (LDS -> bands) + decouple + den + approx write;
//      bands packed as float2 -> b64 LDS ops
//   C: 3x3 CM conv (LDS float2) -> num;  block reduce -> atomics
// acc layout: [REPL][BATCH][4][6] = {den_h,den_v,den_d,num_h,num_v,num_d}
// --------------------------------------------------------------------------
__global__ __launch_bounds__(NTHR) void
fused_kernel(const float* __restrict__ srcR, const float* __restrict__ srcD,
             long srcBatchStride, int H, int W, int H2, int W2,
             float* __restrict__ outAR, float* __restrict__ outAD,
             int left, int top, int right, int bottom,
             float rfh, float rfv, float rfd,
             float* __restrict__ acc, int scale)
{
    const float LO0 =  0.48296291314469f,  LO1 =  0.836516303737469f,
                LO2 =  0.224143868041857f, LO3 = -0.129409522550921f;
    const float HI0 = -0.129409522550921f, HI1 = -0.224143868041857f,
                HI2 =  0.836516303737469f, HI3 = -0.48296291314469f;

    __shared__ float sVloR[HTH][VP], sVhiR[HTH][VP];
    __shared__ float sVloD[HTH][VP], sVhiD[HTH][VP];
    __shared__ float2 sA[HTH][HTP];   // (|rf_h*Ah|, |rf_v*Av|)
    __shared__ float2 sB[HTH][HTP];   // (|rf_d*Ad|, Rh)
    __shared__ float2 sC[HTH][HTP];   // (Rv, Rd)
    __shared__ float smem[8][6];

    int b  = blockIdx.z;
    int X0 = blockIdx.x * FBX;
    int Y0 = blockIdx.y * FBY;
    int tid = threadIdx.y * FBX + threadIdx.x;

    const float* pR = srcR + (long)b * srcBatchStride;
    const float* pD = srcD + (long)b * srcBatchStride;

    // ---- Phase A: vertical db2 filter, row-paired ----
    // pair lp covers output rows ly=2lp, 2lp+1 using source rows rb..rb+5
    bool interior = (X0 >= 2) && (2 * X0 + SRW - 4 < W) &&
                    (Y0 >= 2) && (2 * Y0 + 4 * (HTH / 2 - 1) + 2 < H);
    if (interior) {
        for (int i = tid; i < SRW * (HTH / 2); i += NTHR) {
            int c = i % SRW, lp = i / SRW;
            int ly = 2 * lp;
            int gc = 2 * X0 - 3 + c;
            int rb = 2 * Y0 + 4 * lp - 3;
            int q = rb * W + gc;
            float r0 = pR[q], r1 = pR[q + W], r2 = pR[q + 2 * W],
                  r3 = pR[q + 3 * W], r4 = pR[q + 4 * W], r5 = pR[q + 5 * W];
            sVloR[ly][c]     = LO0 * r0 + LO1 * r1 + LO2 * r2 + LO3 * r3;
            sVhiR[ly][c]     = HI0 * r0 + HI1 * r1 + HI2 * r2 + HI3 * r3;
            sVloR[ly + 1][c] = LO0 * r2 + LO1 * r3 + LO2 * r4 + LO3 * r5;
            sVhiR[ly + 1][c] = HI0 * r2 + HI1 * r3 + HI2 * r4 + HI3 * r5;
            float d0 = pD[q], d1 = pD[q + W], d2 = pD[q + 2 * W],
                  d3 = pD[q + 3 * W], d4 = pD[q + 4 * W], d5 = pD[q + 5 * W];
            sVloD[ly][c]     = LO0 * d0 + LO1 * d1 + LO2 * d2 + LO3 * d3;
            sVhiD[ly][c]     = HI0 * d0 + HI1 * d1 + HI2 * d2 + HI3 * d3;
            sVloD[ly + 1][c] = LO0 * d2 + LO1 * d3 + LO2 * d4 + LO3 * d5;
            sVhiD[ly + 1][c] = HI0 * d2 + HI1 * d3 + HI2 * d4 + HI3 * d5;
        }
    } else {
        for (int i = tid; i < SRW * (HTH / 2); i += NTHR) {
            int c = i % SRW, lp = i / SRW;
            int ly = 2 * lp;
            int gc = reflect_idx(2 * X0 - 3 + c, W);
            int rb = 2 * Y0 + 4 * lp - 3;
            int q0 = reflect_idx(rb + 0, H) * W + gc;
            int q1 = reflect_idx(rb + 1, H) * W + gc;
            int q2 = reflect_idx(rb + 2, H) * W + gc;
            int q3 = reflect_idx(rb + 3, H) * W + gc;
            int q4 = reflect_idx(rb + 4, H) * W + gc;
            int q5 = reflect_idx(rb + 5, H) * W + gc;
            float r0 = pR[q0], r1 = pR[q1], r2 = pR[q2],
                  r3 = pR[q3], r4 = pR[q4], r5 = pR[q5];
            sVloR[ly][c]     = LO0 * r0 + LO1 * r1 + LO2 * r2 + LO3 * r3;
            sVhiR[ly][c]     = HI0 * r0 + HI1 * r1 + HI2 * r2 + HI3 * r3;
            sVloR[ly + 1][c] = LO0 * r2 + LO1 * r3 + LO2 * r4 + LO3 * r5;
            sVhiR[ly + 1][c] = HI0 * r2 + HI1 * r3 + HI2 * r4 + HI3 * r5;
            float d0 = pD[q0], d1 = pD[q1], d2 = pD[q2],
                  d3 = pD[q3], d4 = pD[q4], d5 = pD[q5];
            sVloD[ly][c]     = LO0 * d0 + LO1 * d1 + LO2 * d2 + LO3 * d3;
            sVhiD[ly][c]     = HI0 * d0 + HI1 * d1 + HI2 * d2 + HI3 * d3;
            sVloD[ly + 1][c] = LO0 * d2 + LO1 * d3 + LO2 * d4 + LO3 * d5;
            sVhiD[ly + 1][c] = HI0 * d2 + HI1 * d3 + HI2 * d4 + HI3 * d5;
        }
    }
    __syncthreads();

    float denh = 0.f, denv = 0.f, dend = 0.f;
    float numh = 0.f, numv = 0.f, numd = 0.f;
    int base2 = b * S0;

    // ---- Phase B: horizontal filter + decouple + den + approx write ----
    for (int i = tid; i < HTW * HTH; i += NTHR) {
        int lx = i % HTW, ly = i / HTW;
        int cc = 2 * lx;

        float l0 = sVloR[ly][cc], l1 = sVloR[ly][cc + 1],
              l2 = sVloR[ly][cc + 2], l3 = sVloR[ly][cc + 3];
        float h0 = sVhiR[ly][cc], h1 = sVhiR[ly][cc + 1],
              h2 = sVhiR[ly][cc + 2], h3 = sVhiR[ly][cc + 3];
        float aR = LO0 * l0 + LO1 * l1 + LO2 * l2 + LO3 * l3;
        float ov = HI0 * l0 + HI1 * l1 + HI2 * l2 + HI3 * l3;
        float oh = LO0 * h0 + LO1 * h1 + LO2 * h2 + LO3 * h3;
        float od = HI0 * h0 + HI1 * h1 + HI2 * h2 + HI3 * h3;

        l0 = sVloD[ly][cc]; l1 = sVloD[ly][cc + 1];
        l2 = sVloD[ly][cc + 2]; l3 = sVloD[ly][cc + 3];
        h0 = sVhiD[ly][cc]; h1 = sVhiD[ly][cc + 1];
        h2 = sVhiD[ly][cc + 2]; h3 = sVhiD[ly][cc + 3];
        float aD = LO0 * l0 + LO1 * l1 + LO2 * l2 + LO3 * l3;
        float tv = HI0 * l0 + HI1 * l1 + HI2 * l2 + HI3 * l3;
        float th = LO0 * h0 + LO1 * h1 + LO2 * h2 + LO3 * h3;
        float td = HI0 * h0 + HI1 * h1 + HI2 * h2 + HI3 * h3;

        float rh, rv, rd, ah, av, ad;
        decouple6(oh, ov, od, th, tv, td, rh, rv, rd, ah, av, ad);
        sA[ly][lx] = make_float2(fabsf(rfh * ah), fabsf(rfv * av));
        sB[ly][lx] = make_float2(fabsf(rfd * ad), rh);
        sC[ly][lx] = make_float2(rv, rd);

        int bx = X0 - 1 + lx, by = Y0 - 1 + ly;
        bool center = (lx >= 1) && (lx <= FBX) && (ly >= 1) && (ly <= FBY);
        if (center && bx < W2 && by < H2) {
            int o = base2 + by * W2 + bx;
            outAR[o] = aR;
            outAD[o] = aD;
            if (bx >= left && bx < right && by >= top && by < bottom) {
                float t;
                t = fabsf(rfh * oh); denh += t * t * t;
                t = fabsf(rfv * ov); denv += t * t * t;
                t = fabsf(rfd * od); dend += t * t * t;
            }
        }
    }
    __syncthreads();

    // ---- Phase C: 3x3 CM conv -> num ----
    {
        int bx = X0 + threadIdx.x, by = Y0 + threadIdx.y;
        if (bx >= left && bx < right && by >= top && by < bottom) {
            int lx = threadIdx.x + 1, ly = threadIdx.y + 1;
            const float w0 = 1.f / 30.f, wc = 1.f / 15.f;
            float2 a00 = sA[ly-1][lx-1], a01 = sA[ly-1][lx], a02 = sA[ly-1][lx+1];
            float2 a10 = sA[ly  ][lx-1], a11 = sA[ly  ][lx], a12 = sA[ly  ][lx+1];
            float2 a20 = sA[ly+1][lx-1], a21 = sA[ly+1][lx], a22 = sA[ly+1][lx+1];
            float thrh = wc * a11.x + w0 * (a00.x + a01.x + a02.x + a10.x + a12.x +
                                            a20.x + a21.x + a22.x);
            float thrv = wc * a11.y + w0 * (a00.y + a01.y + a02.y + a10.y + a12.y +
                                            a20.y + a21.y + a22.y);
            float2 b00 = sB[ly-1][lx-1], b01 = sB[ly-1][lx], b02 = sB[ly-1][lx+1];
            float2 b10 = sB[ly  ][lx-1], b11 = sB[ly  ][lx], b12 = sB[ly  ][lx+1];
            float2 b20 = sB[ly+1][lx-1], b21 = sB[ly+1][lx], b22 = sB[ly+1][lx+1];
            float thrd = wc * b11.x + w0 * (b00.x + b01.x + b02.x + b10.x + b12.x +
                                            b20.x + b21.x + b22.x);
            float2 cc_ = sC[ly][lx];
            float t;
            t = fmaxf(fabsf(rfh * b11.y) - thrh, 0.f); numh = t * t * t;
            t = fmaxf(fabsf(rfv * cc_.x) - thrv, 0.f); numv = t * t * t;
            t = fmaxf(fabsf(rfd * cc_.y) - thrd, 0.f); numd = t * t * t;
        }
    }

    // ---- block reduce (512 threads = 8 waves) ----
    float vals[6] = {denh, denv, dend, numh, numv, numd};
    #pragma unroll
    for (int i = 0; i < 6; ++i) {
        float v = vals[i];
        #pragma unroll
        for (int off = 32; off > 0; off >>= 1) v += __shfl_down(v, off, 64);
        vals[i] = v;
    }
    __syncthreads();
    if ((tid & 63) == 0) {
        #pragma unroll
        for (int i = 0; i < 6; ++i) smem[tid >> 6][i] = vals[i];
    }
    __syncthreads();
    if (tid < 6) {
        float s = 0.f;
        #pragma unroll
        for (int w = 0; w < 8; ++w) s += smem[w][tid];
        int repl = (blockIdx.y * gridDim.x + blockIdx.x) % REPL;
        atomicAdd(&acc[(((long)repl * BATCH + b) * 4 + scale) * 6 + tid], s);
    }
}

__global__ void zero_kernel(float* __restrict__ acc)
{
    int i = blockIdx.x * blockDim.x + threadIdx.x;
    if (i < REPL * BATCH * 4 * 6) acc[i] = 0.f;
}

__global__ void final_kernel(const float* __restrict__ acc, float* __restrict__ out,
                             float c0, float c1, float c2, float c3)
{
    __shared__ float tot[BATCH][4][6];
    int t = threadIdx.x;
    if (t < BATCH * 4 * 6) {
        int k = t % 6, s = (t / 6) % 4, b = t / 24;
        float v = 0.f;
        for (int r = 0; r < REPL; ++r)
            v += acc[(((long)r * BATCH + b) * 4 + s) * 6 + k];
        tot[b][s][k] = v;
    }
    __syncthreads();
    if (t < BATCH) {
        float cs[4] = {c0, c1, c2, c3};
        float num = 0.f, den = 0.f;
        for (int s = 0; s < 4; ++s) {
            den += cbrtf(tot[t][s][0]) + cbrtf(tot[t][s][1]) + cbrtf(tot[t][s][2]) + cs[s];
            num += cbrtf(tot[t][s][3]) + cbrtf(tot[t][s][4]) + cbrtf(tot[t][s][5]) + cs[s];
        }
        const float lim = 1e-10f;
        if (num < lim) num = 0.f;
        if (den < lim) den = 0.f;
        out[t] = (den == 0.f) ? 1.f : num / den;
    }
}

// --------------------------------------------------------------------------
extern "C" void kernel_launch(void* const* d_in, const int* in_sizes, int n_in,
                              void* d_out, int out_size, void* d_ws, size_t ws_size,
                              hipStream_t stream)
{
    const float* Xref = (const float*)d_in[0];
    const float* Xdst = (const float*)d_in[1];
    float* out = (float*)d_out;
    float* ws  = (float*)d_ws;

    float* aRefA = ws + (long)0 * BATCH * S0;
    float* aRefB = ws + (long)1 * BATCH * S0;
    float* aDstA = ws + (long)2 * BATCH * S0;
    float* aDstB = ws + (long)3 * BATCH * S0;
    float* acc   = ws + (long)4 * BATCH * S0;

    zero_kernel<<<dim3((REPL * BATCH * 24 + 255) / 256), dim3(256), 0, stream>>>(acc);

    static const float RF[4][3] = {
        {0.017382f, 0.017382f, 0.005891f},
        {0.031985f, 0.031985f, 0.014299f},
        {0.043373f, 0.043373f, 0.024397f},
        {0.045673f, 0.045673f, 0.031313f}};

    int H = 1080, W = 1920;
    long srcStride = (long)H * W;
    const float* sR = Xref;
    const float* sD = Xdst;
    float* pingR[2] = {aRefA, aRefB};
    float* pingD[2] = {aDstA, aDstB};
    float cs[4];

    for (int s = 0; s < 4; ++s) {
        int H2 = (H + 1) / 2, W2 = (W + 1) / 2;
        float* oR = pingR[s & 1];
        float* oD = pingD[s & 1];

        int left   = (int)floor((double)W2 * 0.1 - 0.5);
        int top    = (int)floor((double)H2 * 0.1 - 0.5);
        int right  = W2 - left;
        int bottom = H2 - top;

        dim3 blk(FBX, FBY), grd((W2 + FBX - 1) / FBX, (H2 + FBY - 1) / FBY, BATCH);
        fused_kernel<<<grd, blk, 0, stream>>>(sR, sD, srcStride, H, W, H2, W2,
                                              oR, oD, left, top, right, bottom,
                                              RF[s][0], RF[s][1], RF[s][2], acc, s);

        cs[s] = 3.0f * cbrtf((float)((long)(bottom - top) * (right - left)) / 32.0f);

        sR = oR; sD = oD; srcStride = S0;
        H = H2; W = W2;
    }

    final_kernel<<<dim3(1), dim3(128), 0, stream>>>(acc, out, cs[0], cs[1], cs[2], cs[3]);
}